// Round 5
// baseline (449.635 us; speedup 1.0000x reference)
//
#include <hip/hip_runtime.h>

// CubicBSplineFFD: v (4,3,42,42,42) f32 -> out (4,3,192,192,192) f32.
// Closed form after collapsing the 3 stride-5 transposed convs + crop(5,197):
//   out[m] = sum_{d=0..3} B_d(r/5) * v[a+d],  a = m/5, r = m%5   (per axis)
// Weights: d=0: (1-f)^3/6, d=1: B(f), d=2: B(1-f), d=3: f^3/6, f=r/5.
// All control indices a..a+3 in [0,42) for m in [0,192): no bounds logic.
//
// R5: two-kernel split. Ladder (kernel time = dur - ~218us harness fill):
//   v0 3-phase LDS + stride-5 scalar stores : ~176us
//   v1 3-phase LDS + coalesced f4 stores    : ~146us  (best)
//   v2 barrier-free per-column (bpermute)   : ~170us  (regression: L1 thrash
//      from 23x read amplification + serial per-column chain)
// v2 falsified "store duty cycle" alone; remaining theory: v1's stores are
// coupled to __syncthreads (s_waitcnt vmcnt(0) drains store-acks 3x/block,
// all resident blocks convoyed), so the store stream never reaches the
// depth the 6.3 TB/s fill kernel sustains. Fix: decouple completely.
//   K1: v1's verified stage+A1+A2, then write the 42 xy-convolved control
//       values per column into the OUTPUT buffer (z slots 0..43, overwritten
//       later). 78 MB coalesced stores, no barrier after stores.
//   K2: fill-shaped streaming kernel: one wave per column, 5 L1-overlapping
//       scalar loads of staged controls, v2's HW-verified z-conv lane math,
//       one dense 768B nontemporal f4 store, zero barriers/LDS. 54 iters
//       per wave exactly, no tail. Should approach the 54us write floor.
// K1->K2 visibility via stream ordering (kernel boundary = device fence).

#define CPN 42
#define IMG 192
#define TXX 6       // x tile per K1 block
#define TYY 6       // y tile per K1 block
#define NCX 5
#define NCY 5
#define NCZ 42
#define SXS 44      // padded sxy row stride (11 float4)
#define NTHREADS 256
#define SLICE (CPN * CPN * CPN)
#define NCOLS (12 * IMG * IMG)      // 442368 (sl,x,y) columns
#define K2_BLOCKS 2048              // 8192 waves -> exactly 54 cols/wave

typedef float v4f __attribute__((ext_vector_type(4)));

__device__ __forceinline__ float bsp_w_rt(int r, int d) {
  double f = (double)r / 5.0;
  double g = (double)(5 - r) / 5.0;
  double w;
  if (d == 0)      { w = g * g * g / 6.0; }
  else if (d == 1) { w = 2.0 / 3.0 + (0.5 * f - 1.0) * f * f; }
  else if (d == 2) { w = 2.0 / 3.0 + (0.5 * g - 1.0) * g * g; }
  else             { w = f * f * f / 6.0; }
  return (float)w;
}

// ---- K1: xy-convolve control field; stage 42 z-controls per column into
// the output buffer's z slots 0..43 (slots 42..43 are LDS garbage, later
// overwritten by K2 which only reads z 0..41). ----
__global__ void __launch_bounds__(NTHREADS) ffd_stage1(
    const float* __restrict__ v, float* __restrict__ out) {
  const int tid = threadIdx.x;
  const int bx = blockIdx.x;
  const int by = blockIdx.y;
  const int sl = blockIdx.z;
  const int x0 = bx * TXX;
  const int y0 = by * TYY;
  const int cx0 = x0 / 5;
  const int cy0 = y0 / 5;

  __shared__ float wtab[20];
  __shared__ float vt[NCX * NCY * NCZ];            // 1050 f
  __shared__ float t1[TYY * NCX * NCZ];            // 1260 f
  __shared__ __align__(16) float sxy[TXX * TYY * SXS];  // 1584 f

  if (tid < 20) wtab[tid] = bsp_w_rt(tid >> 2, tid & 3);

  const float* vs = v + (size_t)sl * SLICE;
  for (int l = tid; l < NCX * NCY * NCZ; l += NTHREADS) {
    int cz = l % NCZ;
    int rest = l / NCZ;
    int cy = rest % NCY;
    int cx = rest / NCY;
    vt[l] = vs[((cx0 + cx) * CPN + (cy0 + cy)) * CPN + cz];
  }
  __syncthreads();

  // A1: convolve along y -> t1[yi][cx][cz]
  for (int l = tid; l < TYY * NCX * NCZ; l += NTHREADS) {
    int cz = l % NCZ;
    int rest = l / NCZ;
    int cx = rest % NCX;
    int yi = rest / NCX;
    int y = y0 + yi;
    int ay = y / 5;
    int ry = y - 5 * ay;
    int cyo = ay - cy0;                    // 0 or 1
    const float* wr = &wtab[ry * 4];
    const float* vp = &vt[(cx * NCY + cyo) * NCZ + cz];
    float acc = wr[0] * vp[0] + wr[1] * vp[NCZ]
              + wr[2] * vp[2 * NCZ] + wr[3] * vp[3 * NCZ];
    t1[(yi * NCX + cx) * NCZ + cz] = acc;
  }
  __syncthreads();

  // A2: convolve along x -> sxy[xi*TYY+yi][cz]
  for (int l = tid; l < TXX * TYY * NCZ; l += NTHREADS) {
    int cz = l % NCZ;
    int rest = l / NCZ;
    int yi = rest % TYY;
    int xi = rest / TYY;
    int x = x0 + xi;
    int ax = x / 5;
    int rx = x - 5 * ax;
    int cxo = ax - cx0;                    // 0 or 1
    const float* wr = &wtab[rx * 4];
    const float* tp = &t1[(yi * NCX + cxo) * NCZ + cz];
    float acc = wr[0] * tp[0] + wr[1] * tp[NCZ]
              + wr[2] * tp[2 * NCZ] + wr[3] * tp[3 * NCZ];
    sxy[(xi * TYY + yi) * SXS + cz] = acc;
  }
  __syncthreads();

  // stage out: 36 cols x 11 float4 (44 f; 42..43 = don't-care garbage)
  float* os = out + (size_t)sl * ((size_t)IMG * IMG * IMG);
  for (int l = tid; l < TXX * TYY * 11; l += NTHREADS) {
    int qq = l % 11;
    int xy = l / 11;
    int yi = xy % TYY;
    int xi = xy / TYY;
    v4f val = *reinterpret_cast<const v4f*>(&sxy[xy * SXS + 4 * qq]);
    *reinterpret_cast<v4f*>(
        os + (size_t)((x0 + xi) * IMG + (y0 + yi)) * IMG + 4 * qq) = val;
  }
}

// ---- K2: z-convolve each column in place. One wave per column per iter:
// lane q (<48) produces out z = 4q..4q+3 from staged controls c0..c0+4.
// Loads complete into registers before the overwrite (in-wave dataflow);
// columns are partitioned across waves, so no cross-wave hazard. ----
__global__ void __launch_bounds__(NTHREADS) ffd_stage2(
    const float* __restrict__ src, float* __restrict__ dst) {
  const int lane = threadIdx.x & 63;
  const int gw = (blockIdx.x * NTHREADS + threadIdx.x) >> 6;
  const int nw = (K2_BLOCKS * NTHREADS) >> 6;     // 8192 waves

  const int q = lane < 48 ? lane : 47;            // lanes 48..63: clamp
  const int c0 = (4 * q) / 5;                     // 0..37
  float wz[4][5];                                  // dense 5-tap per k
#pragma unroll
  for (int k = 0; k < 4; ++k) {
    int z = 4 * q + k;
    int c = z / 5;
    int r = z - 5 * c;
    int off = c - c0;                              // 0 or 1
#pragma unroll
    for (int t = 0; t < 5; ++t) {
      int d = t - off;
      wz[k][t] = (d >= 0 && d < 4) ? bsp_w_rt(r, d) : 0.0f;
    }
  }

#pragma unroll 2
  for (int n = gw; n < NCOLS; n += nw) {          // exactly 54 iterations
    const float* cp = src + (size_t)n * IMG;
    float s0 = cp[c0];
    float s1 = cp[c0 + 1];
    float s2 = cp[c0 + 2];
    float s3 = cp[c0 + 3];
    float s4 = cp[c0 + 4];
    v4f res;
#pragma unroll
    for (int k = 0; k < 4; ++k) {
      float a = wz[k][0] * s0;
      a = fmaf(wz[k][1], s1, a);
      a = fmaf(wz[k][2], s2, a);
      a = fmaf(wz[k][3], s3, a);
      a = fmaf(wz[k][4], s4, a);
      res[k] = a;
    }
    if (lane < 48) {
      __builtin_nontemporal_store(
          res, reinterpret_cast<v4f*>(dst + (size_t)n * IMG + 4 * q));
    }
  }
}

extern "C" void kernel_launch(void* const* d_in, const int* in_sizes, int n_in,
                              void* d_out, int out_size, void* d_ws, size_t ws_size,
                              hipStream_t stream) {
  (void)in_sizes; (void)n_in; (void)d_ws; (void)ws_size; (void)out_size;
  const float* v = (const float*)d_in[0];
  float* out = (float*)d_out;
  dim3 g1(IMG / TXX, IMG / TYY, 12);              // 32 x 32 x 12
  ffd_stage1<<<g1, NTHREADS, 0, stream>>>(v, out);
  ffd_stage2<<<K2_BLOCKS, NTHREADS, 0, stream>>>(out, out);
}

// Round 7
// 349.750 us; speedup vs baseline: 1.2856x; 1.2856x over previous
//
#include <hip/hip_runtime.h>

// CubicBSplineFFD: v (4,3,42,42,42) f32 -> out (4,3,192,192,192) f32.
// Closed form after collapsing the 3 stride-5 transposed convs + crop(5,197):
//   out[m] = sum_{d=0..3} B_d(r/5) * v[a+d],  a = m/5, r = m%5   (per axis)
// Weights: d=0: (1-f)^3/6, d=1: B(f), d=2: B(1-f), d=3: f^3/6, f=r/5.
// All control indices a..a+3 in [0,42) for m in [0,192): no bounds logic.
//
// R7 = R6 resubmitted verbatim: R6 died to GPU-acquisition timeout (broker
// at capacity) — never executed. Static audit clean; measuring before any
// further mutation.
//
// Ladder (kernel time = dur - harness re-poison fill, fill-rate-normalized):
//   v0 3-phase LDS tile + stride-5 scalar stores : ~176us
//   v1 3-phase LDS tile + coalesced f4 stores    : ~146us  (best so far)
//   v2 barrier-free per-column bpermute          : ~170us
//   v3 two-kernel split (stage->out, stream z)   : ~181us (normalized)
// v2+v3 falsified store *scheduling* theories (duty cycle, barrier drain).
// R6 theory: the gap to the 6.2 TB/s fill is WRITE ADDRESS LOCALITY. All
// prior versions write 36 scattered 768B chunks per block across a 5.5MB
// window, interleaved across XCDs -> L2 evicts fragmented bursts -> DRAM
// row-buffer thrash (~2.3-3 TB/s cap). The fill writes long linear ranges.
// Fix: one block per (sl,x) writes out[sl][x][:][:] = 147KB CONTIGUOUS,
// XCD-chunk swizzle gives each XCD a contiguous ~42MB region.
//   A1: x-conv, 4 coalesced L2-hot plane loads -> t1[42][42] (LDS)
//   A2: y-conv -> t2[192][42] (LDS, 32KB)
//   B : z-conv per column (K2's verified per-lane wz/c0 math), one dense
//       768B wave-store per y, linear march. 3 barriers, no store drains.
// LDS 39.4KB -> 4 blocks/CU; weights via wq[5] (depend only on m%5).

#define CPN 42
#define IMG 192
#define NTHREADS 256
#define SLICE (CPN * CPN * CPN)   // 74088
#define PLANE (CPN * CPN)         // 1764
#define NBLK (12 * IMG)           // 2304 blocks = (sl, x)

typedef float v4f __attribute__((ext_vector_type(4)));

__device__ __forceinline__ float bsp_w_rt(int r, int d) {
  double f = (double)r / 5.0;
  double g = (double)(5 - r) / 5.0;
  double w;
  if (d == 0)      { w = g * g * g / 6.0; }
  else if (d == 1) { w = 2.0 / 3.0 + (0.5 * f - 1.0) * f * f; }
  else if (d == 2) { w = 2.0 / 3.0 + (0.5 * g - 1.0) * g * g; }
  else             { w = f * f * f / 6.0; }
  return (float)w;
}

__global__ void __launch_bounds__(NTHREADS) ffd_kernel(
    const float* __restrict__ v, float* __restrict__ out) {
  const int tid = threadIdx.x;
  const int bid = blockIdx.x;
  // XCD-chunk bijection (2304 % 8 == 0): XCD k owns a contiguous n-range
  // -> contiguous ~42MB output region per XCD L2.
  const int n  = (bid & 7) * (NBLK / 8) + (bid >> 3);
  const int sl = n / IMG;          // 0..11
  const int x  = n - sl * IMG;     // 0..191
  const int ax = x / 5;            // <= 38; taps ax..ax+3 <= 41
  const int rx = x - 5 * ax;

  __shared__ v4f  wq[5];           // B-spline weights per residue r = m%5
  __shared__ float t1[PLANE];      // x-convolved  [cy][cz]
  __shared__ float t2[IMG * CPN];  // xy-convolved [y][cz]  (32KB)

  if (tid < 5) {
    v4f qv;
    qv.x = bsp_w_rt(tid, 0); qv.y = bsp_w_rt(tid, 1);
    qv.z = bsp_w_rt(tid, 2); qv.w = bsp_w_rt(tid, 3);
    wq[tid] = qv;
  }

  // ---- per-lane z-conv constants (register-only, verified in v2/v3) ----
  const int w    = tid >> 6;
  const int lane = tid & 63;
  const int q    = lane < 48 ? lane : 47;   // lanes 48..63: clamp, no store
  const int c0   = (4 * q) / 5;             // 0..37
  float wz[4][5];
#pragma unroll
  for (int k = 0; k < 4; ++k) {
    int z = 4 * q + k;
    int c = z / 5;
    int r = z - 5 * c;
    int off = c - c0;                       // 0 or 1
#pragma unroll
    for (int t = 0; t < 5; ++t) {
      int d = t - off;
      wz[k][t] = (d >= 0 && d < 4) ? bsp_w_rt(r, d) : 0.0f;
    }
  }
  __syncthreads();                          // wq ready

  // ---- A1: x-conv. 4 contiguous 1764-float planes, fully coalesced,
  // L2-hot (whole 3.5MB input fits in one XCD's 4MB L2). ----
  const float* vp0 = v + (size_t)sl * SLICE + (size_t)ax * PLANE;
  const v4f wx = wq[rx];                    // wave-uniform broadcast
  for (int l = tid; l < PLANE; l += NTHREADS) {
    float a = wx.x * vp0[l];
    a = fmaf(wx.y, vp0[l + PLANE], a);
    a = fmaf(wx.z, vp0[l + 2 * PLANE], a);
    a = fmaf(wx.w, vp0[l + 3 * PLANE], a);
    t1[l] = a;
  }
  __syncthreads();

  // ---- A2: y-conv -> t2[y][cz]. Lanes span <=2 distinct y per instr:
  // wq read is a 2-address broadcast; t1 reads consecutive cz. ----
  for (int l = tid; l < IMG * CPN; l += NTHREADS) {
    int y  = l / CPN;
    int cz = l - y * CPN;
    int ay = y / 5;
    int ry = y - 5 * ay;
    v4f wy = wq[ry];
    const float* tp = &t1[ay * CPN + cz];
    float a = wy.x * tp[0];
    a = fmaf(wy.y, tp[CPN], a);
    a = fmaf(wy.z, tp[2 * CPN], a);
    a = fmaf(wy.w, tp[3 * CPN], a);
    t2[l] = a;
  }
  __syncthreads();

  // ---- B: z-conv per column; one dense 768B wave-store per y; block's
  // stores cover a single linear 147KB range (no drain, no barrier). ----
  float* ob = out + (size_t)n * (IMG * IMG);
  for (int i = 0; i < 48; ++i) {
    int y = w + 4 * i;                      // waves interleave adjacent y
    const float* tp = &t2[y * CPN + c0];
    float s0 = tp[0], s1 = tp[1], s2 = tp[2], s3 = tp[3], s4 = tp[4];
    v4f res;
#pragma unroll
    for (int k = 0; k < 4; ++k) {
      float a = wz[k][0] * s0;
      a = fmaf(wz[k][1], s1, a);
      a = fmaf(wz[k][2], s2, a);
      a = fmaf(wz[k][3], s3, a);
      a = fmaf(wz[k][4], s4, a);
      res[k] = a;
    }
    if (lane < 48)
      *reinterpret_cast<v4f*>(ob + y * IMG + 4 * q) = res;
  }
}

extern "C" void kernel_launch(void* const* d_in, const int* in_sizes, int n_in,
                              void* d_out, int out_size, void* d_ws, size_t ws_size,
                              hipStream_t stream) {
  (void)in_sizes; (void)n_in; (void)d_ws; (void)ws_size; (void)out_size;
  const float* v = (const float*)d_in[0];
  float* out = (float*)d_out;
  ffd_kernel<<<dim3(NBLK), NTHREADS, 0, stream>>>(v, out);
}

// Round 8
// 347.082 us; speedup vs baseline: 1.2955x; 1.0077x over previous
//
#include <hip/hip_runtime.h>

// CubicBSplineFFD: v (4,3,42,42,42) f32 -> out (4,3,192,192,192) f32.
// Closed form after collapsing the 3 stride-5 transposed convs + crop(5,197):
//   out[m] = sum_{d=0..3} B_d(r/5) * v[a+d],  a = m/5, r = m%5   (per axis)
// Weights: d=0: (1-f)^3/6, d=1: B(f), d=2: B(1-f), d=3: f^3/6, f=r/5.
// All control indices a..a+3 in [0,42) for m in [0,192): no bounds logic.
//
// Ladder (kernel time = dur - harness re-poison fill, fill-rate-normalized):
//   v0 3-phase LDS tile + stride-5 scalar stores : ~176us
//   v1 3-phase LDS tile + coalesced f4 stores    : ~146us
//   v2 barrier-free per-column bpermute          : ~170us (L1 thrash)
//   v3 two-kernel split (stage->out, stream z)   : ~181us
//   v4 per-(sl,x) block, 147KB linear writes,
//      XCD-chunk swizzle                         : ~127us  (best)
// v4 post-mortem: locality helped (+13%) but stores still ~2.7 TB/s eff.
// Residual theory: stores exist ONLY in phase B; A1+A2 (no stores) are
// ~40-50% of the block timeline and the 4 resident blocks convoy through
// barriers in lockstep -> HBM write duty ~55% -> 54us floor /0.55 ~= 100us.
// R8 fix: chunked y-pipeline. 192 y-rows in 8 chunks of 24; t2 is a
// double-buffered 24-row chunk (2x4KB instead of 32KB). Steady phase j:
//   { B-store(chunk j) from buf[j&1]  ||  A2-compute(chunk j+1)->buf[~j&1] }
// one barrier per phase -> stores flow in ~90% of phases even in lockstep.
// LDS 39.4KB -> 15.3KB: occupancy 4 -> 8 blocks/CU (32 waves = cap).
// All math (wz/c0 lane mapping, A1/A2 weights, XCD-chunked linear writes)
// is HW-verified from v2..v4; only the y-loop structure changes.

#define CPN 42
#define IMG 192
#define NTHREADS 256
#define SLICE (CPN * CPN * CPN)   // 74088
#define PLANE (CPN * CPN)         // 1764
#define NBLK (12 * IMG)           // 2304 blocks = (sl, x)
#define CHY 24                    // y-chunk rows
#define NCH (IMG / CHY)           // 8 chunks

typedef float v4f __attribute__((ext_vector_type(4)));

__device__ __forceinline__ float bsp_w_rt(int r, int d) {
  double f = (double)r / 5.0;
  double g = (double)(5 - r) / 5.0;
  double w;
  if (d == 0)      { w = g * g * g / 6.0; }
  else if (d == 1) { w = 2.0 / 3.0 + (0.5 * f - 1.0) * f * f; }
  else if (d == 2) { w = 2.0 / 3.0 + (0.5 * g - 1.0) * g * g; }
  else             { w = f * f * f / 6.0; }
  return (float)w;
}

__global__ void __launch_bounds__(NTHREADS) ffd_kernel(
    const float* __restrict__ v, float* __restrict__ out) {
  const int tid = threadIdx.x;
  const int bid = blockIdx.x;
  // XCD-chunk bijection (2304 % 8 == 0): each XCD owns a contiguous
  // n-range -> contiguous ~42MB output region per XCD L2.
  const int n  = (bid & 7) * (NBLK / 8) + (bid >> 3);
  const int sl = n / IMG;          // 0..11
  const int x  = n - sl * IMG;     // 0..191
  const int ax = x / 5;            // <= 38; taps ax..ax+3 <= 41
  const int rx = x - 5 * ax;

  __shared__ v4f  wq[5];                 // weights per residue r = m%5
  __shared__ float t1[PLANE];            // x-convolved [cy][cz]   (7KB)
  __shared__ float t2c[2][CHY * CPN];    // xy-conv chunk, dbuf    (8KB)

  if (tid < 5) {
    v4f qv;
    qv.x = bsp_w_rt(tid, 0); qv.y = bsp_w_rt(tid, 1);
    qv.z = bsp_w_rt(tid, 2); qv.w = bsp_w_rt(tid, 3);
    wq[tid] = qv;
  }

  // ---- per-lane z-conv constants (register-only; verified v2..v4) ----
  const int w    = tid >> 6;
  const int lane = tid & 63;
  const int q    = lane < 48 ? lane : 47;   // lanes 48..63 clamp, no store
  const int c0   = (4 * q) / 5;             // 0..37
  float wz[4][5];
#pragma unroll
  for (int k = 0; k < 4; ++k) {
    int z = 4 * q + k;
    int c = z / 5;
    int r = z - 5 * c;
    int off = c - c0;                       // 0 or 1
#pragma unroll
    for (int t = 0; t < 5; ++t) {
      int d = t - off;
      wz[k][t] = (d >= 0 && d < 4) ? bsp_w_rt(r, d) : 0.0f;
    }
  }
  __syncthreads();                          // wq ready

  // ---- A1: x-conv. 4 contiguous 1764-float planes, coalesced, L2-hot ----
  const float* vp0 = v + (size_t)sl * SLICE + (size_t)ax * PLANE;
  const v4f wx = wq[rx];                    // wave-uniform broadcast
  for (int l = tid; l < PLANE; l += NTHREADS) {
    float a = wx.x * vp0[l];
    a = fmaf(wx.y, vp0[l + PLANE], a);
    a = fmaf(wx.z, vp0[l + 2 * PLANE], a);
    a = fmaf(wx.w, vp0[l + 3 * PLANE], a);
    t1[l] = a;
  }
  __syncthreads();

  // ---- A2 prologue: chunk 0 -> t2c[0] ----
  for (int l = tid; l < CHY * CPN; l += NTHREADS) {
    int yy = l / CPN;
    int cz = l - yy * CPN;
    int y  = yy;                            // chunk 0
    int ay = y / 5;
    int ry = y - 5 * ay;
    v4f wy = wq[ry];
    const float* tp = &t1[ay * CPN + cz];
    float a = wy.x * tp[0];
    a = fmaf(wy.y, tp[CPN], a);
    a = fmaf(wy.z, tp[2 * CPN], a);
    a = fmaf(wy.w, tp[3 * CPN], a);
    t2c[0][l] = a;
  }
  __syncthreads();

  // ---- pipeline: phase j = { B-store(chunk j) || A2(chunk j+1) } ----
  float* ob = out + (size_t)n * (IMG * IMG);
  for (int j = 0; j < NCH; ++j) {
    const float* buf = t2c[j & 1];
    // B: z-conv + dense 768B wave-stores for y in chunk j (6 y per wave)
#pragma unroll
    for (int i = 0; i < CHY / 4; ++i) {
      int yy = w + 4 * i;
      int y  = j * CHY + yy;
      const float* tp = &buf[yy * CPN + c0];
      float s0 = tp[0], s1 = tp[1], s2 = tp[2], s3 = tp[3], s4 = tp[4];
      v4f res;
#pragma unroll
      for (int k = 0; k < 4; ++k) {
        float a = wz[k][0] * s0;
        a = fmaf(wz[k][1], s1, a);
        a = fmaf(wz[k][2], s2, a);
        a = fmaf(wz[k][3], s3, a);
        a = fmaf(wz[k][4], s4, a);
        res[k] = a;
      }
      if (lane < 48)
        *reinterpret_cast<v4f*>(ob + y * IMG + 4 * q) = res;
    }
    // A2: next chunk into the other buffer (disjoint from B's reads)
    if (j + 1 < NCH) {
      float* nbuf = t2c[(j + 1) & 1];
      for (int l = tid; l < CHY * CPN; l += NTHREADS) {
        int yy = l / CPN;
        int cz = l - yy * CPN;
        int y  = (j + 1) * CHY + yy;
        int ay = y / 5;
        int ry = y - 5 * ay;
        v4f wy = wq[ry];
        const float* tp = &t1[ay * CPN + cz];
        float a = wy.x * tp[0];
        a = fmaf(wy.y, tp[CPN], a);
        a = fmaf(wy.z, tp[2 * CPN], a);
        a = fmaf(wy.w, tp[3 * CPN], a);
        nbuf[l] = a;
      }
    }
    __syncthreads();
  }
}

extern "C" void kernel_launch(void* const* d_in, const int* in_sizes, int n_in,
                              void* d_out, int out_size, void* d_ws, size_t ws_size,
                              hipStream_t stream) {
  (void)in_sizes; (void)n_in; (void)d_ws; (void)ws_size; (void)out_size;
  const float* v = (const float*)d_in[0];
  float* out = (float*)d_out;
  ffd_kernel<<<dim3(NBLK), NTHREADS, 0, stream>>>(v, out);
}